// Round 11
// baseline (76.690 us; speedup 1.0000x reference)
//
#include <hip/hip_runtime.h>
#include <hip/hip_bf16.h>

typedef __attribute__((ext_vector_type(4))) float f32x4;
typedef __attribute__((ext_vector_type(8))) short bf16x8;

#define M_TOT 30752   // 8*62*62 output pixels

__device__ __forceinline__ unsigned short f2bf(float f) {
  unsigned int u = __float_as_uint(f);
  u = u + 0x7FFF + ((u >> 16) & 1);   // round-to-nearest-even
  return (unsigned short)(u >> 16);
}

__device__ __forceinline__ void gload16(const void* g, void* l) {
  __builtin_amdgcn_global_load_lds((const __attribute__((address_space(1))) unsigned int*)g,
                                   (__attribute__((address_space(3))) unsigned int*)l,
                                   16, 0, 0);
}

// ---- prep1: blocks 0..4095 cast x->bf16; blocks 4096..4351: keff per o.
__global__ __launch_bounds__(256) void prep1(const float* __restrict__ x,
                                             const float* __restrict__ Q,
                                             const float* __restrict__ S,
                                             unsigned short* __restrict__ xb,
                                             float* __restrict__ Keff) {
  const int bid = blockIdx.x;
  const int t = threadIdx.x;

  if (bid < 4096) {                  // ---- cast x -> bf16 ----
    int i = bid * 256 + t;
    const f32x4* xp = (const f32x4*)x;
    f32x4 a = xp[2 * i];
    f32x4 b = xp[2 * i + 1];
    bf16x8 o;
    o[0] = (short)f2bf(a[0]); o[1] = (short)f2bf(a[1]);
    o[2] = (short)f2bf(a[2]); o[3] = (short)f2bf(a[3]);
    o[4] = (short)f2bf(b[0]); o[5] = (short)f2bf(b[1]);
    o[6] = (short)f2bf(b[2]); o[7] = (short)f2bf(b[3]);
    ((bf16x8*)xb)[i] = o;
    return;
  }

  const int o = bid - 4096;          // 0..255
  float s[16];
  const float* sp = S + (o >> 4) * 4096 + (o & 15) * 256 + t;   // coalesced across f
#pragma unroll
  for (int bi = 0; bi < 16; ++bi) s[bi] = sp[bi * 65536];
  const float* qp = Q + o * 144;                                 // uniform -> s_load
#pragma unroll
  for (int kk = 0; kk < 9; ++kk) {
    float a = 0.f;
#pragma unroll
    for (int bi = 0; bi < 16; ++bi) a = fmaf(qp[kk * 16 + bi], s[bi], a);
    Keff[(o * 9 + kk) * 256 + t] = a;
  }
}

// ---- prep2: K2t[kk][f][ci] = sum_o P[o][ci] * Keff[o][kk][f]  (bf16, transposed)
__global__ __launch_bounds__(256) void k2t_k(const float* __restrict__ P,
                                             const float* __restrict__ Keff,
                                             unsigned short* __restrict__ K2t) {
  const int kk = blockIdx.x >> 6;        // 0..8
  const int f0 = (blockIdx.x & 63) * 4;  // 0..252
  const int ci = threadIdx.x;
  float acc[4] = {0.f, 0.f, 0.f, 0.f};
#pragma unroll 8
  for (int o = 0; o < 256; ++o) {
    float pv = P[o * 256 + ci];                        // coalesced
    const float* ke = Keff + (o * 9 + kk) * 256 + f0;  // uniform -> s_load_dwordx4
    acc[0] = fmaf(pv, ke[0], acc[0]);
    acc[1] = fmaf(pv, ke[1], acc[1]);
    acc[2] = fmaf(pv, ke[2], acc[2]);
    acc[3] = fmaf(pv, ke[3], acc[3]);
  }
#pragma unroll
  for (int j = 0; j < 4; ++j)
    K2t[kk * 65536 + (f0 + j) * 256 + ci] = f2bf(acc[j]);
}

// ---- main: implicit-GEMM conv.  M=30752, N=256, K=2304.
// BM=128, BN=256, BK=64/step; waves (sk, wn) in 2x4, each a 128x64 tile over
// its K-half. Conflict-free 64B-row swizzle (R10, verified 0 conflicts).
// STEP restructured for read/MFMA overlap: bfr[0..3] read FIRST, af staggered
// 2-at-a-time into 4 sub-phases of 8 MFMAs -> first MFMA waits 6 reads (was 9),
// later groups 2 reads deeper; counted lgkmcnt overlaps the LDS port with the
// MFMA stream. Triple-buffer, depth-2 prefetch, counted vmcnt(6), setprio.
__global__ __launch_bounds__(512, 2) void conv_gemm(const unsigned short* __restrict__ xb,
                                                    const unsigned short* __restrict__ K2t,
                                                    float* __restrict__ out) {
  __shared__ __attribute__((aligned(16))) char smem[147456];   // 144KB
  unsigned short* const A0 = (unsigned short*)(smem);            // 16KB: [2 sk][128 m][64B]
  unsigned short* const B0 = (unsigned short*)(smem + 16384);    // 32KB: [2 sk][256 f][64B]
  unsigned short* const A1 = (unsigned short*)(smem + 49152);
  unsigned short* const B1 = (unsigned short*)(smem + 65536);
  unsigned short* const A2 = (unsigned short*)(smem + 98304);
  unsigned short* const B2 = (unsigned short*)(smem + 114688);
  float* const red = (float*)smem;                               // 64KB, after main loop

  const int tid = threadIdx.x;
  const int lane = tid & 63;
  const int sk = tid >> 8;          // k-half 0..1
  const int wn = (tid >> 6) & 3;    // n-quarter 0..3
  const int m0 = blockIdx.x * 128;

  const int rl = lane & 15;
  const int kg = lane >> 4;

  // staging: thread t owns A chunks {t, t+512} (row t>>2, slot t&3, sk 0/1)
  // and B chunks {t, t+512, t+1024, t+1536}. Source slot pre-swizzled:
  // s_src = (t&3) ^ ((row>>1)&3) = (t&3) ^ ((t>>3)&3)  [row = t>>2]
  const int s_src = ((tid & 3) ^ ((tid >> 3) & 3)) * 8;   // element offset
  int gAa;                          // A pixel base addr (elements), slot folded
  {
    int m = m0 + (tid >> 2); if (m >= M_TOT) m = M_TOT - 1;
    int b = m / 3844; int rem = m - b * 3844;
    int h = rem / 62; int w = rem - h * 62;
    gAa = ((b * 64 + h) * 64 + w) * 256 + s_src;
  }
  const int fB0 = (tid >> 2) * 256 + s_src;            // B row base (elements)
  const int fB1 = ((tid >> 2) + 128) * 256 + s_src;    // row+128: same swizzle bits

  f32x4 zero = {0.f, 0.f, 0.f, 0.f};
  f32x4 acc[8][4];
#pragma unroll
  for (int i = 0; i < 8; ++i)
#pragma unroll
    for (int j = 0; j < 4; ++j) acc[i][j] = zero;

  // read-side: slot = kg ^ ((rl>>1)&3); row-repeats (+16) keep swizzle bits
  const int slotr = (kg ^ ((rl >> 1) & 3)) * 16;                    // bytes
  const int aoff = sk * 8192 + rl * 64 + slotr;                     // bytes
  const int boff = sk * 16384 + (wn * 64 + rl) * 64 + slotr;        // bytes

#define STAGE(t, bufA, bufB)                                                   \
  {                                                                            \
    int kk_ = (t) >> 2, cb_ = (t) & 3;                                         \
    int kh_ = kk_ / 3, kw_ = kk_ - kh_ * 3;                                    \
    int offA_ = kh_ * 16384 + kw_ * 256 + cb_ * 64;                            \
    int offB_ = kk_ * 65536 + cb_ * 64;                                        \
    gload16(xb + gAa + offA_,       &bufA[tid * 8]);                           \
    gload16(xb + gAa + offA_ + 32,  &bufA[(tid + 512) * 8]);                   \
    gload16(K2t + offB_ + fB0,      &bufB[tid * 8]);                           \
    gload16(K2t + offB_ + fB1,      &bufB[(tid + 512) * 8]);                   \
    gload16(K2t + offB_ + fB0 + 32, &bufB[(tid + 1024) * 8]);                  \
    gload16(K2t + offB_ + fB1 + 32, &bufB[(tid + 1536) * 8]);                  \
  }

#define STEP(t, cA, cB, nA, nB)                                                \
  {                                                                            \
    if ((t) == 35) asm volatile("s_waitcnt vmcnt(0)" ::: "memory");            \
    else           asm volatile("s_waitcnt vmcnt(6)" ::: "memory");            \
    __builtin_amdgcn_sched_barrier(0);                                         \
    __builtin_amdgcn_s_barrier();                                              \
    __builtin_amdgcn_sched_barrier(0);                                         \
    if ((t) < 34) { STAGE((t) + 2, nA, nB); }                                  \
    bf16x8 bfr[4];                                                             \
    _Pragma("unroll")                                                          \
    for (int ni = 0; ni < 4; ++ni)                                             \
      bfr[ni] = *(const bf16x8*)((const char*)(cB) + boff + ni * 1024);        \
    bf16x8 a0 = *(const bf16x8*)((const char*)(cA) + aoff);                    \
    bf16x8 a1 = *(const bf16x8*)((const char*)(cA) + aoff + 1024);             \
    _Pragma("unroll")                                                          \
    for (int j = 0; j < 4; ++j) {                                              \
      bf16x8 a2, a3;                                                           \
      if (j < 3) {                                                             \
        a2 = *(const bf16x8*)((const char*)(cA) + aoff + (2 * j + 2) * 1024);  \
        a3 = *(const bf16x8*)((const char*)(cA) + aoff + (2 * j + 3) * 1024);  \
      }                                                                        \
      __builtin_amdgcn_s_setprio(1);                                           \
      _Pragma("unroll")                                                        \
      for (int ni = 0; ni < 4; ++ni)                                           \
        acc[2 * j][ni] = __builtin_amdgcn_mfma_f32_16x16x32_bf16(              \
            a0, bfr[ni], acc[2 * j][ni], 0, 0, 0);                             \
      _Pragma("unroll")                                                        \
      for (int ni = 0; ni < 4; ++ni)                                           \
        acc[2 * j + 1][ni] = __builtin_amdgcn_mfma_f32_16x16x32_bf16(          \
            a1, bfr[ni], acc[2 * j + 1][ni], 0, 0, 0);                         \
      __builtin_amdgcn_s_setprio(0);                                           \
      a0 = a2; a1 = a3;                                                        \
    }                                                                          \
  }

  STAGE(0, A0, B0);
  STAGE(1, A1, B1);

  for (int tt = 0; tt < 12; ++tt) {
    int t0 = tt * 3;
    STEP(t0,     A0, B0, A2, B2);
    STEP(t0 + 1, A1, B1, A0, B0);
    STEP(t0 + 2, A2, B2, A1, B1);
  }

  __syncthreads();   // main loop done; smem reused as reduction buffer

  // epilogue: sk=1 waves stage acc in LDS; sk=0 adds + stores.
  // D row = kg*4 + r (+16*mi), col = rl (+16*ni +64*wn).
#pragma unroll
  for (int round = 0; round < 2; ++round) {
    if (sk == 1) {
#pragma unroll
      for (int mc = 0; mc < 4; ++mc)
#pragma unroll
        for (int ni = 0; ni < 4; ++ni)
          *(f32x4*)((char*)red + (((wn * 4 + mc) * 4 + ni) * 64 + lane) * 16) =
              acc[round * 4 + mc][ni];
    }
    __syncthreads();
    if (sk == 0) {
#pragma unroll
      for (int mc = 0; mc < 4; ++mc) {
        int mi = round * 4 + mc;
        int mb = m0 + mi * 16 + kg * 4;
#pragma unroll
        for (int ni = 0; ni < 4; ++ni) {
          f32x4 o = *(f32x4*)((char*)red + (((wn * 4 + mc) * 4 + ni) * 64 + lane) * 16);
          o += acc[mi][ni];
          int f = wn * 64 + ni * 16 + rl;
#pragma unroll
          for (int r = 0; r < 4; ++r) {
            int m = mb + r;
            if (m < M_TOT) out[m * 256 + f] = o[r];
          }
        }
      }
    }
    __syncthreads();
  }
#undef STAGE
#undef STEP
}

extern "C" void kernel_launch(void* const* d_in, const int* in_sizes, int n_in,
                              void* d_out, int out_size, void* d_ws, size_t ws_size,
                              hipStream_t stream) {
  const float* x = (const float*)d_in[0];   // [8,64,64,256]
  const float* P = (const float*)d_in[1];   // [256,256]
  const float* Q = (const float*)d_in[2];   // [256,3,3,16]
  const float* S = (const float*)d_in[3];   // [256,16,256]
  float* out = (float*)d_out;               // [8,62,62,256]

  char* ws = (char*)d_ws;
  unsigned short* xb   = (unsigned short*)ws;                        // 16,777,216 B
  unsigned short* K2t  = (unsigned short*)(ws + 16777216);           //  1,179,648 B
  float*          Keff = (float*)(ws + 16777216 + 1179648);          //  2,359,296 B

  prep1<<<4096 + 256, 256, 0, stream>>>(x, Q, S, xb, Keff);
  k2t_k<<<576, 256, 0, stream>>>(P, Keff, K2t);
  conv_gemm<<<241, 512, 0, stream>>>(xb, K2t, out);
}